// Round 2
// baseline (1140.742 us; speedup 1.0000x reference)
//
#include <hip/hip_runtime.h>

// LoRAConnector: B=4, T=2048, N=4, C=1024, A=8, nC=4096, SINKHORN_ITERS=20
//
// Round 3: LDS-staged phi via global_load_lds double-buffer.
//  R1 post-mortem: depth-3 reg pipeline was defeated by the compiler — t-loop
//  not fully unrolled -> sl=t%3 runtime-indexed reg arrays -> scratch (the
//  +48MB WRITE_SIZE = 96B/thread), VGPR stayed 88, loads sank back to uses.
//  Fix: stage each 64-row phi tile (24 KB: pp 4K + po 4K + pr 16K) into LDS
//  with global_load_lds (6 x 16B per thread per tile), double-buffered.
//  __syncthreads drains vmcnt -> race-free; loads issue one full tile
//  (~550 cy consume) before the barrier that needs them -> ~zero drain stall.
//  LDS dest must be linear (m104), so bank-conflict fix is the pre-swizzled
//  GLOBAL source (m173 pattern), involution XOR applied on both sides:
//   pp/po: s' = s ^ ((s>>3)&3)   (flips bits 0,1 with l's bits 1,2)
//   pr:    u' = u ^ ((u>>4)&7)   (flips bits 0..2 with l's bits 0..2)
//  -> wave's 16 unique ds_read_b128 addrs spread over 8 bank-groups (2-way
//  residual aliasing = free per m136). Without this, pr reads are 16-way.
//  LDS 48K+red -> 3 blocks/CU; __launch_bounds__(256,4) caps VGPR at 128
//  (live set evidence from R0: xs64+acc25 ~= 88, headroom for addressing).

#define BT 8192        // B*T tokens
#define NC 4096        // N*C
#define NC4 1024       // NC/4

__global__ __launch_bounds__(256, 4) void lora_connector_kernel(
    const float* __restrict__ x,
    const float* __restrict__ inw,
    const float* __restrict__ phi_pre,
    const float* __restrict__ phi_post,
    const float* __restrict__ phi_res,
    const float* __restrict__ b_pre,
    const float* __restrict__ b_post,
    const float* __restrict__ b_res,
    const float* __restrict__ alpha_pre,
    const float* __restrict__ alpha_post,
    const float* __restrict__ alpha_res,
    const int*   __restrict__ adapter_indices,
    float* __restrict__ out)
{
    const int tid = threadIdx.x;
    const int g   = tid & 3;        // which of the block's 4 tokens
    const int l   = tid >> 2;       // d4-slice 0..63
    const int wvid= tid >> 6;       // wave 0..3
    const int ln  = tid & 63;       // lane within wave
    const int tok = blockIdx.x * 4 + g;
    const int b   = blockIdx.x >> 9;          // tok / 2048, block-uniform
    const int idx = adapter_indices[b];

    const float4* __restrict__ x4p = (const float4*)x + (size_t)tok * NC4;
    const float4* __restrict__ w4p = (const float4*)inw + (size_t)idx * NC4;
    const float4* __restrict__ pp4 = (const float4*)(phi_pre  + (size_t)idx * (NC * 4));
    const float4* __restrict__ po4 = (const float4*)(phi_post + (size_t)idx * (NC * 4));
    const float4* __restrict__ pr4 = (const float4*)(phi_res  + (size_t)idx * (NC * 16));

    // double-buffered phi tile staging (24 KB per buffer)
    __shared__ float4 ppL[2][256];
    __shared__ float4 poL[2][256];
    __shared__ float4 prL[2][1024];
    __shared__ float red[4][4][26];

    // ---- staging helper (emitted inline; mt/bf are compile-time under unroll)
    // wave wvid stages chunks c = 6*wvid .. 6*wvid+5 (1 KB each, linear LDS,
    // pre-swizzled per-lane global source).
    #define STAGE_TILE(MT, BF)                                                   \
    {                                                                            \
        _Pragma("unroll")                                                        \
        for (int i = 0; i < 6; ++i) {                                            \
            const int c = wvid * 6 + i;                                          \
            if (c < 4) {                                                         \
                const int sp = (c << 6) | ln;                                    \
                const float4* gsrc = pp4 + (MT) * 256 + (sp ^ ((sp >> 3) & 3));  \
                __builtin_amdgcn_global_load_lds(                                \
                    (const __attribute__((address_space(1))) void*)gsrc,         \
                    (__attribute__((address_space(3))) void*)&ppL[BF][c << 6],   \
                    16, 0, 0);                                                   \
            } else if (c < 8) {                                                  \
                const int sp = ((c - 4) << 6) | ln;                              \
                const float4* gsrc = po4 + (MT) * 256 + (sp ^ ((sp >> 3) & 3));  \
                __builtin_amdgcn_global_load_lds(                                \
                    (const __attribute__((address_space(1))) void*)gsrc,         \
                    (__attribute__((address_space(3))) void*)&poL[BF][(c - 4) << 6], \
                    16, 0, 0);                                                   \
            } else {                                                             \
                const int up = ((c - 8) << 6) | ln;                              \
                const float4* gsrc = pr4 + (MT) * 1024 + (up ^ ((up >> 4) & 7)); \
                __builtin_amdgcn_global_load_lds(                                \
                    (const __attribute__((address_space(1))) void*)gsrc,         \
                    (__attribute__((address_space(3))) void*)&prL[BF][(c - 8) << 6], \
                    16, 0, 0);                                                   \
            }                                                                    \
        }                                                                        \
    }

    // ---- Prologue: stage tile 0, load x, first w tile, sumsq ----
    STAGE_TILE(0, 0);

    float4 xs[16];
    #pragma unroll
    for (int m = 0; m < 16; ++m) xs[m] = x4p[m * 64 + l];

    float4 wnx = w4p[l];

    float acc[25];
    #pragma unroll
    for (int j = 0; j < 24; ++j) acc[j] = 0.0f;
    {
        float ssum = 0.0f;
        #pragma unroll
        for (int m = 0; m < 16; ++m) {
            const float4 v = xs[m];
            ssum = fmaf(v.x, v.x, fmaf(v.y, v.y, fmaf(v.z, v.z, fmaf(v.w, v.w, ssum))));
        }
        acc[24] = ssum;
    }

    // ---- Phase 1: 16 tiles; barrier -> stage next -> consume current ----
    #pragma unroll
    for (int m = 0; m < 16; ++m) {
        const int bf = m & 1;
        __syncthreads();                       // tile m resident (vmcnt drained)
        if (m + 1 < 16) STAGE_TILE(m + 1, bf ^ 1);   // fly during consume

        const float4 xv = xs[m];
        const float4 wv = wnx;
        if (m + 1 < 16) wnx = w4p[(m + 1) * 64 + l]; // w one tile ahead
        const float xw[4] = { xv.x * wv.x, xv.y * wv.y, xv.z * wv.z, xv.w * wv.w };

        #pragma unroll
        for (int e = 0; e < 4; ++e) {
            const float s = xw[e];
            const int sidx = (l << 2) | e;
            const int sswz = sidx ^ ((sidx >> 3) & 3);
            const float4 a = ppL[bf][sswz];
            acc[0] = fmaf(s, a.x, acc[0]); acc[1] = fmaf(s, a.y, acc[1]);
            acc[2] = fmaf(s, a.z, acc[2]); acc[3] = fmaf(s, a.w, acc[3]);
            const float4 p = poL[bf][sswz];
            acc[4] = fmaf(s, p.x, acc[4]); acc[5] = fmaf(s, p.y, acc[5]);
            acc[6] = fmaf(s, p.z, acc[6]); acc[7] = fmaf(s, p.w, acc[7]);
            #pragma unroll
            for (int q = 0; q < 4; ++q) {
                const int u = (l << 4) | (e << 2) | q;
                const float4 r = prL[bf][u ^ ((u >> 4) & 7)];
                acc[8 + q * 4 + 0] = fmaf(s, r.x, acc[8 + q * 4 + 0]);
                acc[8 + q * 4 + 1] = fmaf(s, r.y, acc[8 + q * 4 + 1]);
                acc[8 + q * 4 + 2] = fmaf(s, r.z, acc[8 + q * 4 + 2]);
                acc[8 + q * 4 + 3] = fmaf(s, r.w, acc[8 + q * 4 + 3]);
            }
        }
    }

    // ---- Phase 2a: intra-wave butterfly over lane bits 2..5 (16 slices/token) ----
    #pragma unroll
    for (int j = 0; j < 25; ++j) {
        float v = acc[j];
        v += __shfl_xor(v, 4);
        v += __shfl_xor(v, 8);
        v += __shfl_xor(v, 16);
        v += __shfl_xor(v, 32);
        acc[j] = v;
    }

    // ---- Phase 2b: cross-wave reduction via LDS ----
    __syncthreads();                 // all ds_reads of prL[...] done everywhere
    if ((ln >> 2) == 0) {            // lanes 0..3: lane == g
        #pragma unroll
        for (int j = 0; j < 25; ++j) red[wvid][g][j] = acc[j];
    }
    __syncthreads();
    float tot[25];
    #pragma unroll
    for (int j = 0; j < 25; ++j)
        tot[j] = (red[0][g][j] + red[1][g][j]) + (red[2][g][j] + red[3][g][j]);

    // ---- Phase 2c: rms, gates, sinkhorn ----
    const float inv_rms = rsqrtf(tot[24] * (1.0f / 4096.0f) + 1e-5f);
    const float apre  = alpha_pre[idx];
    const float apost = alpha_post[idx];
    const float ares  = alpha_res[idx];

    float Hpre[4], Hpost[4];
    #pragma unroll
    for (int n = 0; n < 4; ++n) {
        const float zp = fmaf(apre,  tot[n]     * inv_rms, b_pre[idx * 4 + n]);
        Hpre[n]  = 1.0f / (1.0f + __expf(-zp));
        const float zq = fmaf(apost, tot[4 + n] * inv_rms, b_post[idx * 4 + n]);
        Hpost[n] = 2.0f / (1.0f + __expf(-zq));
    }

    // lane owns element (si,sj) of token g's 4x4 matrix
    const int s16 = ln >> 2;         // 0..15
    const int sj = s16 & 3;
    const int si = s16 >> 2;
    float Mv = __expf(fmaf(ares, tot[8 + si * 4 + sj] * inv_rms,
                           b_res[idx * 16 + si * 4 + sj]));
    #pragma unroll
    for (int it = 0; it < 20; ++it) {
        float rs = Mv + __shfl_xor(Mv, 4);   // sum over j (lane bits 2,3)
        rs += __shfl_xor(rs, 8);
        Mv *= __builtin_amdgcn_rcpf(rs);
        float cs = Mv + __shfl_xor(Mv, 16);  // sum over i (lane bits 4,5)
        cs += __shfl_xor(cs, 32);
        Mv *= __builtin_amdgcn_rcpf(cs);
    }

    // gather full W[i][j] = M[i][j] + Hpost[i]*Hpre[j] for this thread's token
    float W[4][4];
    #pragma unroll
    for (int ss = 0; ss < 16; ++ss) {
        const float mm = __shfl(Mv, ss * 4 + g);
        W[ss >> 2][ss & 3] = fmaf(Hpost[ss >> 2], Hpre[ss & 3], mm);
    }

    // ---- Phase 3: out[i,c] = sum_j W[i][j] * x[j,c], all from registers ----
    float4* __restrict__ out4 = (float4*)out + (size_t)tok * NC4;
    #pragma unroll
    for (int k = 0; k < 4; ++k) {
        const int c4 = k * 64 + l;
        const float4 x0 = xs[0 * 4 + k];
        const float4 x1 = xs[1 * 4 + k];
        const float4 x2 = xs[2 * 4 + k];
        const float4 x3 = xs[3 * 4 + k];
        #pragma unroll
        for (int i = 0; i < 4; ++i) {
            float4 o;
            o.x = fmaf(W[i][0], x0.x, fmaf(W[i][1], x1.x, fmaf(W[i][2], x2.x, W[i][3] * x3.x)));
            o.y = fmaf(W[i][0], x0.y, fmaf(W[i][1], x1.y, fmaf(W[i][2], x2.y, W[i][3] * x3.y)));
            o.z = fmaf(W[i][0], x0.z, fmaf(W[i][1], x1.z, fmaf(W[i][2], x2.z, W[i][3] * x3.z)));
            o.w = fmaf(W[i][0], x0.w, fmaf(W[i][1], x1.w, fmaf(W[i][2], x2.w, W[i][3] * x3.w)));
            out4[i * 256 + c4] = o;
        }
    }
    #undef STAGE_TILE
}

extern "C" void kernel_launch(void* const* d_in, const int* in_sizes, int n_in,
                              void* d_out, int out_size, void* d_ws, size_t ws_size,
                              hipStream_t stream) {
    const float* x         = (const float*)d_in[0];
    const float* inw       = (const float*)d_in[1];
    const float* phi_pre   = (const float*)d_in[2];
    const float* phi_post  = (const float*)d_in[3];
    const float* phi_res   = (const float*)d_in[4];
    const float* b_pre     = (const float*)d_in[5];
    const float* b_post    = (const float*)d_in[6];
    const float* b_res     = (const float*)d_in[7];
    const float* alpha_pre = (const float*)d_in[8];
    const float* alpha_post= (const float*)d_in[9];
    const float* alpha_res = (const float*)d_in[10];
    const int*   adapter   = (const int*)d_in[11];
    float* out = (float*)d_out;

    dim3 grid(BT / 4);   // 2048 blocks, 4 tokens each
    dim3 block(256);
    lora_connector_kernel<<<grid, block, 0, stream>>>(
        x, inw, phi_pre, phi_post, phi_res,
        b_pre, b_post, b_res,
        alpha_pre, alpha_post, alpha_res,
        adapter, out);
}

// Round 3
// 323.879 us; speedup vs baseline: 3.5221x; 3.5221x over previous
//
#include <hip/hip_runtime.h>

// LoRAConnector: B=4, T=2048, N=4, C=1024, A=8, nC=4096, SINKHORN_ITERS=20
//
// Round 4: m97-shaped 2-phase pipeline (rolled loop), no xs[] registers.
//  R2 post-mortem: full unroll + xs[16] + infeasible launch_bounds(256,4)
//  (needs LDS<=40K, had 50K) -> bound discarded, VGPR=256, ~3KB/thread
//  scratch (= the +2.4GB HBM). Staging + swizzle algebra itself verified.
//  Fixes:
//   - #pragma unroll 1 m-loop, runtime bf (LDS index, not reg index).
//   - xs[] dropped: R0's VGPR=88 proves compiler never kept it anyway;
//     phase 3 re-reads x (same addrs, ~48KB/CU footprint -> L1/L2 hits).
//   - single fused LDS tile: dest = &tileL[bf][c*64] uniform for all 24
//     chunks (pp c=0..3, po c=4..7, pr c=8..23); staging descriptors
//     (ptr,stride) precomputed once, statically indexed after unroll.
//   - plain __launch_bounds__(256); LDS 51.2KB -> 3 blocks/CU (12 waves).
//  Bank-conflict fix unchanged (verified in R2): pre-swizzled GLOBAL source
//  (m173 / rule #21 both-sides involution), same XOR on the ds_read side:
//   pp/po: s' = s ^ ((s>>3)&3);  pr: u' = u ^ ((u>>4)&7)  -> 2-way residual.

#define BT 8192        // B*T tokens
#define NC 4096        // N*C
#define NC4 1024       // NC/4

__global__ __launch_bounds__(256) void lora_connector_kernel(
    const float* __restrict__ x,
    const float* __restrict__ inw,
    const float* __restrict__ phi_pre,
    const float* __restrict__ phi_post,
    const float* __restrict__ phi_res,
    const float* __restrict__ b_pre,
    const float* __restrict__ b_post,
    const float* __restrict__ b_res,
    const float* __restrict__ alpha_pre,
    const float* __restrict__ alpha_post,
    const float* __restrict__ alpha_res,
    const int*   __restrict__ adapter_indices,
    float* __restrict__ out)
{
    const int tid = threadIdx.x;
    const int g   = tid & 3;        // which of the block's 4 tokens
    const int l   = tid >> 2;       // d4-slice 0..63
    const int wvid= tid >> 6;       // wave 0..3
    const int ln  = tid & 63;       // lane within wave
    const int tok = blockIdx.x * 4 + g;
    const int b   = blockIdx.x >> 9;          // tok / 2048, block-uniform
    const int idx = adapter_indices[b];

    const float4* __restrict__ x4p = (const float4*)x + (size_t)tok * NC4;
    const float4* __restrict__ w4p = (const float4*)inw + (size_t)idx * NC4;
    const float4* __restrict__ pp4 = (const float4*)(phi_pre  + (size_t)idx * (NC * 4));
    const float4* __restrict__ po4 = (const float4*)(phi_post + (size_t)idx * (NC * 4));
    const float4* __restrict__ pr4 = (const float4*)(phi_res  + (size_t)idx * (NC * 16));

    // fused double-buffered phi tile: [0..255]=pp, [256..511]=po, [512..1535]=pr
    __shared__ float4 tileL[2][1536];
    __shared__ float red[4][4][26];

    // ---- staging descriptors: wave wvid owns chunks c = 6*wvid .. 6*wvid+5.
    // Each chunk = 64 lanes x 16B = 1KB, linear LDS dest &tileL[bf][c*64],
    // pre-swizzled per-lane global source. Static-indexed after unroll.
    const float4* sg[6];
    int sstr[6];
    #pragma unroll
    for (int i = 0; i < 6; ++i) {
        const int c = wvid * 6 + i;              // wave-uniform
        const int sp  = ((c & 3) << 6) | ln;     // pp/po element index
        const int sps = sp ^ ((sp >> 3) & 3);
        const int up  = ((c - 8) << 6) | ln;     // pr element index (c>=8)
        const int ups = up ^ ((up >> 4) & 7);
        const float4* a = (c < 4) ? (pp4 + sps) : (po4 + sps);
        sg[i]   = (c < 8) ? a : (pr4 + ups);
        sstr[i] = (c < 8) ? 256 : 1024;
    }

    #define STAGE_TILE(MT, BF)                                                   \
    {                                                                            \
        _Pragma("unroll")                                                        \
        for (int i = 0; i < 6; ++i) {                                            \
            __builtin_amdgcn_global_load_lds(                                    \
                (const __attribute__((address_space(1))) void*)(sg[i] + (size_t)(MT) * sstr[i]), \
                (__attribute__((address_space(3))) void*)&tileL[BF][(wvid * 6 + i) << 6], \
                16, 0, 0);                                                       \
        }                                                                        \
    }

    // ---- Prologue: stage tile 0 ----
    STAGE_TILE(0, 0);

    float acc[25];
    #pragma unroll
    for (int j = 0; j < 25; ++j) acc[j] = 0.0f;
    float ssum = 0.0f;

    // ---- Phase 1: 16 tiles; barrier -> stage next -> consume current ----
    #pragma unroll 1
    for (int m = 0; m < 16; ++m) {
        const int bf = m & 1;
        __syncthreads();                         // tile m resident (vmcnt drain)
        if (m < 15) STAGE_TILE(m + 1, bf ^ 1);   // in flight during consume

        const float4 xv = x4p[m * 64 + l];
        const float4 wv = w4p[m * 64 + l];
        ssum = fmaf(xv.x, xv.x, fmaf(xv.y, xv.y, fmaf(xv.z, xv.z, fmaf(xv.w, xv.w, ssum))));
        const float xw[4] = { xv.x * wv.x, xv.y * wv.y, xv.z * wv.z, xv.w * wv.w };

        #pragma unroll
        for (int e = 0; e < 4; ++e) {
            const float s = xw[e];
            const int sidx = (l << 2) | e;
            const int sswz = sidx ^ ((sidx >> 3) & 3);
            const float4 a = tileL[bf][sswz];
            acc[0] = fmaf(s, a.x, acc[0]); acc[1] = fmaf(s, a.y, acc[1]);
            acc[2] = fmaf(s, a.z, acc[2]); acc[3] = fmaf(s, a.w, acc[3]);
            const float4 p = tileL[bf][256 + sswz];
            acc[4] = fmaf(s, p.x, acc[4]); acc[5] = fmaf(s, p.y, acc[5]);
            acc[6] = fmaf(s, p.z, acc[6]); acc[7] = fmaf(s, p.w, acc[7]);
            #pragma unroll
            for (int q = 0; q < 4; ++q) {
                const int u = (l << 4) | (e << 2) | q;
                const float4 r = tileL[bf][512 + (u ^ ((u >> 4) & 7))];
                acc[8 + q * 4 + 0] = fmaf(s, r.x, acc[8 + q * 4 + 0]);
                acc[8 + q * 4 + 1] = fmaf(s, r.y, acc[8 + q * 4 + 1]);
                acc[8 + q * 4 + 2] = fmaf(s, r.z, acc[8 + q * 4 + 2]);
                acc[8 + q * 4 + 3] = fmaf(s, r.w, acc[8 + q * 4 + 3]);
            }
        }
    }
    acc[24] = ssum;

    // ---- Phase 2a: intra-wave butterfly over lane bits 2..5 (16 slices/token) ----
    #pragma unroll
    for (int j = 0; j < 25; ++j) {
        float v = acc[j];
        v += __shfl_xor(v, 4);
        v += __shfl_xor(v, 8);
        v += __shfl_xor(v, 16);
        v += __shfl_xor(v, 32);
        acc[j] = v;
    }

    // ---- Phase 2b: cross-wave reduction via LDS ----
    __syncthreads();
    if ((ln >> 2) == 0) {            // lanes 0..3: lane == g
        #pragma unroll
        for (int j = 0; j < 25; ++j) red[wvid][g][j] = acc[j];
    }
    __syncthreads();
    float tot[25];
    #pragma unroll
    for (int j = 0; j < 25; ++j)
        tot[j] = (red[0][g][j] + red[1][g][j]) + (red[2][g][j] + red[3][g][j]);

    // ---- Phase 2c: rms, gates, sinkhorn ----
    const float inv_rms = rsqrtf(tot[24] * (1.0f / 4096.0f) + 1e-5f);
    const float apre  = alpha_pre[idx];
    const float apost = alpha_post[idx];
    const float ares  = alpha_res[idx];

    float Hpre[4], Hpost[4];
    #pragma unroll
    for (int n = 0; n < 4; ++n) {
        const float zp = fmaf(apre,  tot[n]     * inv_rms, b_pre[idx * 4 + n]);
        Hpre[n]  = 1.0f / (1.0f + __expf(-zp));
        const float zq = fmaf(apost, tot[4 + n] * inv_rms, b_post[idx * 4 + n]);
        Hpost[n] = 2.0f / (1.0f + __expf(-zq));
    }

    // lane owns element (si,sj) of token g's 4x4 matrix
    const int s16 = ln >> 2;         // 0..15
    const int sj = s16 & 3;
    const int si = s16 >> 2;
    float Mv = __expf(fmaf(ares, tot[8 + si * 4 + sj] * inv_rms,
                           b_res[idx * 16 + si * 4 + sj]));
    #pragma unroll
    for (int it = 0; it < 20; ++it) {
        float rs = Mv + __shfl_xor(Mv, 4);   // sum over j (lane bits 2,3)
        rs += __shfl_xor(rs, 8);
        Mv *= __builtin_amdgcn_rcpf(rs);
        float cs = Mv + __shfl_xor(Mv, 16);  // sum over i (lane bits 4,5)
        cs += __shfl_xor(cs, 32);
        Mv *= __builtin_amdgcn_rcpf(cs);
    }

    // gather full W[i][j] = M[i][j] + Hpost[i]*Hpre[j] for this thread's token
    float W[4][4];
    #pragma unroll
    for (int ss = 0; ss < 16; ++ss) {
        const float mm = __shfl(Mv, ss * 4 + g);
        W[ss >> 2][ss & 3] = fmaf(Hpost[ss >> 2], Hpre[ss & 3], mm);
    }

    // ---- Phase 3: out[tok][i*256+c4] = sum_j W[i][j] * x[tok][j*256+c4] ----
    // x re-read (same 16 addresses this thread touched in phase 1 -> cache-hot)
    float4* __restrict__ out4 = (float4*)out + (size_t)tok * NC4;
    #pragma unroll
    for (int k = 0; k < 4; ++k) {
        const int c4 = k * 64 + l;
        const float4 x0 = x4p[0 * 256 + c4];
        const float4 x1 = x4p[1 * 256 + c4];
        const float4 x2 = x4p[2 * 256 + c4];
        const float4 x3 = x4p[3 * 256 + c4];
        #pragma unroll
        for (int i = 0; i < 4; ++i) {
            float4 o;
            o.x = fmaf(W[i][0], x0.x, fmaf(W[i][1], x1.x, fmaf(W[i][2], x2.x, W[i][3] * x3.x)));
            o.y = fmaf(W[i][0], x0.y, fmaf(W[i][1], x1.y, fmaf(W[i][2], x2.y, W[i][3] * x3.y)));
            o.z = fmaf(W[i][0], x0.z, fmaf(W[i][1], x1.z, fmaf(W[i][2], x2.z, W[i][3] * x3.z)));
            o.w = fmaf(W[i][0], x0.w, fmaf(W[i][1], x1.w, fmaf(W[i][2], x2.w, W[i][3] * x3.w)));
            out4[i * 256 + c4] = o;
        }
    }
    #undef STAGE_TILE
}

extern "C" void kernel_launch(void* const* d_in, const int* in_sizes, int n_in,
                              void* d_out, int out_size, void* d_ws, size_t ws_size,
                              hipStream_t stream) {
    const float* x         = (const float*)d_in[0];
    const float* inw       = (const float*)d_in[1];
    const float* phi_pre   = (const float*)d_in[2];
    const float* phi_post  = (const float*)d_in[3];
    const float* phi_res   = (const float*)d_in[4];
    const float* b_pre     = (const float*)d_in[5];
    const float* b_post    = (const float*)d_in[6];
    const float* b_res     = (const float*)d_in[7];
    const float* alpha_pre = (const float*)d_in[8];
    const float* alpha_post= (const float*)d_in[9];
    const float* alpha_res = (const float*)d_in[10];
    const int*   adapter   = (const int*)d_in[11];
    float* out = (float*)d_out;

    dim3 grid(BT / 4);   // 2048 blocks, 4 tokens each
    dim3 block(256);
    lora_connector_kernel<<<grid, block, 0, stream>>>(
        x, inw, phi_pre, phi_post, phi_res,
        b_pre, b_post, b_res,
        alpha_pre, alpha_post, alpha_res,
        adapter, out);
}